// Round 5
// baseline (1259.016 us; speedup 1.0000x reference)
//
#include <hip/hip_runtime.h>
#include <cstdint>
#include <cmath>

typedef _Float16 f16;
typedef _Float16 f16x8 __attribute__((ext_vector_type(8)));
typedef float f32x4 __attribute__((ext_vector_type(4)));

#define DEVI static __device__ __forceinline__

constexpr int B_ = 1024, S_ = 512, H_ = 2048, R_ = 64, G_ = 16, L_ = 4, A_ = 256;
constexpr float ADAPT = 0.1f;

// async global->LDS, 16B per lane. Dest is wave-uniform base + lane*16 (HW).
DEVI void gl_lds16(const void* g, void* l) {
  __builtin_amdgcn_global_load_lds((const __attribute__((address_space(1))) void*)g,
                                   (__attribute__((address_space(3))) void*)l,
                                   16, 0, 0);
}

__global__ void cvt_f16_kernel(const float* __restrict__ src, f16* __restrict__ dst, int n) {
  int i = blockIdx.x * blockDim.x + threadIdx.x;
  if (i < n) dst[i] = (f16)src[i];
}

// src [rows][cols] fp32 -> dst [cols][rows] f16 (×scale), batched over blockIdx.z.
__global__ void transpose_cvt_kernel(const float* __restrict__ src, f16* __restrict__ dst,
                                     int rows, int cols, float scale) {
  src += (size_t)blockIdx.z * rows * cols;
  dst += (size_t)blockIdx.z * rows * cols;
  __shared__ float tile[32][33];
  const int tx = threadIdx.x, ty = threadIdx.y;
  const int r0 = blockIdx.y * 32, c0 = blockIdx.x * 32;
  #pragma unroll
  for (int i = ty; i < 32; i += 8)
    tile[i][tx] = src[(size_t)(r0 + i) * cols + (c0 + tx)];
  __syncthreads();
  #pragma unroll
  for (int i = ty; i < 32; i += 8)
    dst[(size_t)(c0 + i) * rows + (r0 + tx)] = (f16)(tile[tx][i] * scale);
}

// ============================================================================
// 8-phase 256x256 main GEMM, one-phase REGISTER LOOKAHEAD:
// phase = { read frags for NEXT quadrant ; stage ; [vmcnt] ; barrier ;
//           MFMA on frags read LAST phase ; barrier }
// so DS-pipe read service overlaps the matrix pipe.
//   Out = elu( Aacts[16384,2048] @ Wm^T + b1 + Z1[16384,64] @ (0.1*Wb)^T + 0.1*b2 )
// ============================================================================

#define MQ(QM, QN, AF, BF)                                                   \
  _Pragma("unroll") for (int i = 0; i < 4; ++i)                              \
  _Pragma("unroll") for (int j = 0; j < 2; ++j)                              \
  _Pragma("unroll") for (int k = 0; k < 2; ++k)                              \
    acc[QM][QN][i][j] = __builtin_amdgcn_mfma_f32_16x16x32_f16(              \
        AF[i][k], BF[j][k], acc[QM][QN][i][j], 0, 0, 0)

#define STGM(BASE, OFF, DST) do {                                            \
    gl_lds16(BASE + OFF, &lds[DST]);                                         \
    gl_lds16(BASE + OFF + 32768, &lds[DST + 1024]);                          \
    OFF += 128; DST ^= 65536; } while (0)
#define STGC(BASE, OFF, DST) do {                                            \
    gl_lds16(BASE + OFF, &lds[DST]);                                         \
    gl_lds16(BASE + OFF + 1024, &lds[DST + 1024]);                           \
    DST ^= 65536; } while (0)
#define NOSTG ((void)0)
#define WV8 asm volatile("s_waitcnt vmcnt(8)")
#define WV6 asm volatile("s_waitcnt vmcnt(6)")
#define WV4 asm volatile("s_waitcnt vmcnt(4)")
#define WV0 asm volatile("s_waitcnt vmcnt(0)")
#define NOW ((void)0)
#define NORD ((void)0)
#define BARS do { __builtin_amdgcn_s_barrier(); \
                  __builtin_amdgcn_sched_barrier(0); } while (0)
#define PRI1 __builtin_amdgcn_s_setprio(1)
#define PRI0 __builtin_amdgcn_s_setprio(0)

#define RD_A0(P) do { _Pragma("unroll") for (int i = 0; i < 4; ++i) {        \
    fa0[i][0] = *(const f16x8*)&lds[(P) + cab + i * 2048 + lof0];            \
    fa0[i][1] = *(const f16x8*)&lds[(P) + cab + i * 2048 + lof1]; } } while (0)
#define RD_A1(P) do { _Pragma("unroll") for (int i = 0; i < 4; ++i) {        \
    fa1[i][0] = *(const f16x8*)&lds[(P) + cab + 16384 + i * 2048 + lof0];    \
    fa1[i][1] = *(const f16x8*)&lds[(P) + cab + 16384 + i * 2048 + lof1]; } } while (0)
#define RD_B0(P) do { _Pragma("unroll") for (int j = 0; j < 2; ++j) {        \
    fb0[j][0] = *(const f16x8*)&lds[(P) + cbb + j * 2048 + lof0];            \
    fb0[j][1] = *(const f16x8*)&lds[(P) + cbb + j * 2048 + lof1]; } } while (0)
#define RD_B1(P) do { _Pragma("unroll") for (int j = 0; j < 2; ++j) {        \
    fb1[j][0] = *(const f16x8*)&lds[(P) + cbb + 16384 + j * 2048 + lof0];    \
    fb1[j][1] = *(const f16x8*)&lds[(P) + cbb + 16384 + j * 2048 + lof1]; } } while (0)

// PC/PN: current/next tile LDS buffer base (0 or 65536).
// Reads in phase p feed the MFMA of phase p+1; RD4 (b0 next) after Q4's MFMA.
#define TILE(PC, PN, S1, S2, S3, S4, W2, W3, W4, RD3, RD4) do {              \
    RD_B1(PC); S1; BARS;                                                     \
    PRI1; MQ(0, 0, fa0, fb0); PRI0; BARS;                                    \
    RD_A1(PC); S2; W2; BARS;                                                 \
    PRI1; MQ(0, 1, fa0, fb1); PRI0; BARS;                                    \
    RD3; S3; W3; BARS;                                                       \
    PRI1; MQ(1, 1, fa1, fb1); PRI0; BARS;                                    \
    S4; BARS;                                                                \
    PRI1; MQ(1, 0, fa1, fb0); PRI0; RD4; W4; BARS;                           \
  } while (0)

__global__ __launch_bounds__(512, 2)
void gemm8_main_kernel(const f16* __restrict__ Aacts,   // [16384][2048]
                      const f16* __restrict__ Wm,       // [2048][2048] W_main^T
                      const f16* __restrict__ Z1,       // [16384][64]
                      const f16* __restrict__ Wb2,      // [G][2048][64] 0.1*Wb^T
                      const float* __restrict__ b1,     // [2048]
                      const float* __restrict__ b2,     // [G][2048]
                      f16* __restrict__ Out) {          // [16384][2048]
  __shared__ __align__(16) char lds[131072];
  const int tid = threadIdx.x, lane = tid & 63, wid = tid >> 6;
  // XCD-aware swizzle: 512 blocks, 8 XCDs.
  const int swz = (blockIdx.x & 7) * 64 + (blockIdx.x >> 3);
  const int bm0 = (swz & 63) * 256, bn0 = (swz >> 6) * 256;
  const int g = bm0 >> 10;
  const char* GA = (const char*)Aacts;
  const char* GB = (const char*)Wm;
  const char* GZ = (const char*)Z1;
  const char* GW2 = (const char*)(Wb2 + (size_t)g * H_ * R_);
  const float* b2g = b2 + (size_t)g * H_;

  // staging source permutation (inverse of read swizzle)
  const int srow8 = lane >> 3;
  const int scolb = ((lane & 7) ^ srow8) * 16;
  // fragment read addressing
  const int fr = lane & 15, fq = lane >> 4;
  const uint32_t lof0 = fr * 128 + ((fq * 16) ^ ((fr & 7) << 4));
  const uint32_t lof1 = lof0 ^ 64;

  const uint32_t rA0 = bm0 + wid * 16 + srow8;
  const uint32_t rB0 = bn0 + wid * 16 + srow8;
  uint32_t oA0 = rA0 * 4096 + scolb;
  uint32_t oA1 = oA0 + 128 * 4096;
  uint32_t oB0 = rB0 * 4096 + scolb;
  uint32_t oB1 = oB0 + 128 * 4096;
  uint32_t dA0 = wid * 2048;
  uint32_t dA1 = 16384 + wid * 2048;
  uint32_t dB0 = 32768 + wid * 2048;
  uint32_t dB1 = 49152 + wid * 2048;
  const uint32_t cab = (wid >> 2) * 8192;
  const uint32_t cbb = 32768 + (wid & 3) * 4096;

  f32x4 acc[2][2][4][2] = {};   // [Qm][Qn][i][j]
  f16x8 fa0[4][2], fa1[4][2], fb0[2][2], fb1[2][2];

  // prologue: stage tile0 (A0,B0,A1,B1) + tile1 (A0,B0,A1); retire tile0;
  // pre-read a0(0), b0(0) for tile0's Q1.
  STGM(GA, oA0, dA0);
  STGM(GB, oB0, dB0);
  STGM(GA, oA1, dA1);
  STGM(GB, oB1, dB1);
  STGM(GA, oA0, dA0);
  STGM(GB, oB0, dB0);
  STGM(GA, oA1, dA1);
  WV6;
  BARS;
  RD_A0(0);
  RD_B0(0);

  // steady: tiles 0..29 (parity alternates), staging all-main (tiles <= 31)
  #pragma unroll 1
  for (int it = 0; it < 15; ++it) {
    TILE(0, 65536,
         STGM(GB, oB1, dB1), STGM(GA, oA0, dA0),
         STGM(GB, oB0, dB0), STGM(GA, oA1, dA1),
         WV8, WV8, WV6, RD_A0(65536), RD_B0(65536));
    TILE(65536, 0,
         STGM(GB, oB1, dB1), STGM(GA, oA0, dA0),
         STGM(GB, oB0, dB0), STGM(GA, oA1, dA1),
         WV8, WV8, WV6, RD_A0(0), RD_B0(0));
  }

  // t=30 (parity 0): B1(31) main; A0/B0/A1 of tile 32 = concat (128B rows)
  {
    uint32_t oA0c = rA0 * 128 + scolb;
    uint32_t oA1c = oA0c + 128 * 128;
    uint32_t oB0c = rB0 * 128 + scolb;
    uint32_t oB1c = oB0c + 128 * 128;
    TILE(0, 65536,
         STGM(GB, oB1, dB1), STGC(GZ, oA0c, dA0),
         STGC(GW2, oB0c, dB0), STGC(GZ, oA1c, dA1),
         WV8, WV8, WV6, RD_A0(65536), RD_B0(65536));
    // t=31 (parity 1): B1(32) concat; drain ladder 6/4/0
    TILE(65536, 0,
         STGC(GW2, oB1c, dB1), NOSTG, NOSTG, NOSTG,
         WV6, WV4, WV0, RD_A0(0), RD_B0(0));
  }
  // t=32 (parity 0): concat compute only
  TILE(0, 65536, NOSTG, NOSTG, NOSTG, NOSTG, NOW, NOW, NOW, NORD, NORD);

  // epilogue: v = acc + b1[col] + 0.1*b2[col]; ELU; f16 store
  #pragma unroll
  for (int Qn = 0; Qn < 2; ++Qn) {
    #pragma unroll
    for (int j = 0; j < 2; ++j) {
      const int col = bn0 + Qn * 128 + (wid & 3) * 32 + j * 16 + fr;
      const float bb1 = b1[col];
      const float bb2 = ADAPT * b2g[col];
      #pragma unroll
      for (int Qm = 0; Qm < 2; ++Qm) {
        #pragma unroll
        for (int i = 0; i < 4; ++i) {
          #pragma unroll
          for (int r = 0; r < 4; ++r) {
            const int row = bm0 + Qm * 128 + (wid >> 2) * 64 + i * 16 + fq * 4 + r;
            float v = acc[Qm][Qn][i][j][r] + bb1 + bb2;
            v = v > 0.f ? v : expm1f(v);
            Out[(size_t)row * H_ + col] = (f16)v;
          }
        }
      }
    }
  }
}

enum { EPI_Z1 = 0, EPI_MAIN = 1, EPI_OUT = 2, EPI_L0 = 3 };

// m97-structure GEMM for the small/odd-shaped ops.
template <int BM, int BN, int WM, int WN, int EPI>
__global__ __launch_bounds__((BM / WM) * (BN / WN) * 64)
void gemm_f16_kernel(const f16* __restrict__ A, long long lda, long long Az,
                     const f16* __restrict__ Bw, long long ldb, long long Bz,
                     const f16* __restrict__ A2, long long lda2,
                     const f16* __restrict__ B2w, long long ldb2, long long B2z,
                     int NT1, int NT2,
                     const float* __restrict__ bias1, long long b1z,
                     const float* __restrict__ bias2, long long b2z,
                     const f16* __restrict__ addmat,
                     void* __restrict__ outp, long long out_z, long long ldo,
                     int rows_per_group) {
  constexpr int NW = (BM / WM) * (BN / WN);
  constexpr int FM = WM / 16, FN = WN / 16;
  constexpr int RA = BM / (NW * 16), RB = BN / (NW * 16);
  const int tid = threadIdx.x, lane = tid & 63, wid = tid >> 6;
  const int bm0 = blockIdx.x * BM, bn0 = blockIdx.y * BN;
  const int z = blockIdx.z;
  const int gidx = (rows_per_group > 0) ? (bm0 / rows_per_group) : 0;

  __shared__ __align__(16) f16 As[BM * 32];
  __shared__ __align__(16) f16 Bs[BN * 32];

  const int wm0 = (wid / (BN / WN)) * WM;
  const int wn0 = (wid % (BN / WN)) * WN;
  const int srow = wid * 16 + (lane >> 2);
  const int scol = (lane & 3) * 8;
  const int fr = lane & 15, fq = lane >> 4;

  f32x4 acc[FM][FN] = {};

  const f16* arp = &As[(wm0 + fr) * 32 + fq * 8];
  const f16* brp = &Bs[(wn0 + fr) * 32 + fq * 8];
  auto compute = [&]() {
    f16x8 af[FM], bf[FN];
    #pragma unroll
    for (int i = 0; i < FM; ++i) af[i] = *(const f16x8*)(arp + i * 16 * 32);
    #pragma unroll
    for (int j = 0; j < FN; ++j) bf[j] = *(const f16x8*)(brp + j * 16 * 32);
    #pragma unroll
    for (int i = 0; i < FM; ++i)
      #pragma unroll
      for (int j = 0; j < FN; ++j)
        acc[i][j] = __builtin_amdgcn_mfma_f32_16x16x32_f16(af[i], bf[j], acc[i][j], 0, 0, 0);
  };

  if (NT1 > 0) {
    const f16* pa = A + (long long)z * Az + (long long)(bm0 + srow) * lda + scol;
    const f16* pb = Bw + (long long)z * Bz + (long long)(bn0 + srow) * ldb + scol;
    const long long stA = (long long)(NW * 16) * lda;
    const long long stB = (long long)(NW * 16) * ldb;
    for (int kt = 0; kt < NT1; ++kt) {
      #pragma unroll
      for (int r = 0; r < RA; ++r) gl_lds16(pa + r * stA, &As[(r * NW + wid) * 512]);
      #pragma unroll
      for (int r = 0; r < RB; ++r) gl_lds16(pb + r * stB, &Bs[(r * NW + wid) * 512]);
      pa += 32; pb += 32;
      __syncthreads();
      compute();
      __syncthreads();
    }
  }
  if (NT2 > 0) {
    const f16* pa = A2 + (long long)(bm0 + srow) * lda2 + scol;
    const f16* pb = B2w + (long long)gidx * B2z + (long long)(bn0 + srow) * ldb2 + scol;
    const long long stA = (long long)(NW * 16) * lda2;
    const long long stB = (long long)(NW * 16) * ldb2;
    for (int kt = 0; kt < NT2; ++kt) {
      #pragma unroll
      for (int r = 0; r < RA; ++r) gl_lds16(pa + r * stA, &As[(r * NW + wid) * 512]);
      #pragma unroll
      for (int r = 0; r < RB; ++r) gl_lds16(pb + r * stB, &Bs[(r * NW + wid) * 512]);
      pa += 32; pb += 32;
      __syncthreads();
      compute();
      __syncthreads();
    }
  }

  const float* b1p = bias1 ? bias1 + (long long)z * b1z : nullptr;
  const float* b2p = bias2 ? bias2 + (long long)gidx * b2z : nullptr;
  #pragma unroll
  for (int i = 0; i < FM; ++i) {
    #pragma unroll
    for (int j = 0; j < FN; ++j) {
      const int col = bn0 + wn0 + j * 16 + fr;
      const float b1 = b1p ? b1p[col] : 0.f;
      const float b2v = b2p ? ADAPT * b2p[col] : 0.f;
      #pragma unroll
      for (int r = 0; r < 4; ++r) {
        const int row = bm0 + wm0 + i * 16 + fq * 4 + r;
        float v = acc[i][j][r] + b1 + b2v;
        if constexpr (EPI == EPI_MAIN) {
          v = v > 0.f ? v : expm1f(v);
          ((f16*)outp)[(long long)row * ldo + col] = (f16)v;
        } else if constexpr (EPI == EPI_L0) {
          v += (float)addmat[(long long)(row & (B_ - 1)) * H_ + col];
          v = v > 0.f ? v : expm1f(v);
          ((f16*)outp)[(long long)row * ldo + col] = (f16)v;
        } else if constexpr (EPI == EPI_Z1) {
          ((f16*)outp)[(long long)z * out_z + (long long)row * ldo + col] = (f16)v;
        } else {
          const int g = row >> 10, b = row & 1023;
          ((float*)outp)[((long long)b * G_ + g) * A_ + col] = v;
        }
      }
    }
  }
}

extern "C" void kernel_launch(void* const* d_in, const int* in_sizes, int n_in,
                              void* d_out, int out_size, void* d_ws, size_t ws_size,
                              hipStream_t stream) {
  const float* s      = (const float*)d_in[0];
  const float* W_in   = (const float*)d_in[1];
  const float* b_in   = (const float*)d_in[2];
  const float* W_main = (const float*)d_in[3];
  const float* b_main = (const float*)d_in[4];
  const float* Wa     = (const float*)d_in[5];
  const float* ba     = (const float*)d_in[6];
  const float* Wb     = (const float*)d_in[7];
  const float* bb     = (const float*)d_in[8];
  const float* W_out  = (const float*)d_in[9];
  const float* b_out  = (const float*)d_in[10];

  char* ws = (char*)d_ws;
  size_t off = 0;
  auto alloc = [&](size_t bytes) -> void* {
    void* p = ws + off;
    off += (bytes + 255) & ~(size_t)255;
    return p;
  };
  f16* sh   = (f16*)alloc((size_t)B_ * S_ * 2);
  f16* Wint = (f16*)alloc((size_t)H_ * S_ * 2);
  f16* Wmt  = (f16*)alloc((size_t)L_ * H_ * H_ * 2);
  f16* Wat  = (f16*)alloc((size_t)L_ * G_ * R_ * H_ * 2);
  f16* Wbt  = (f16*)alloc((size_t)L_ * G_ * H_ * R_ * 2);
  f16* Wot  = (f16*)alloc((size_t)A_ * H_ * 2);
  f16* xh0  = (f16*)alloc((size_t)G_ * B_ * H_ * 2);
  f16* xh1  = (f16*)alloc((size_t)G_ * B_ * H_ * 2);
  f16* z1h  = (f16*)alloc((size_t)G_ * B_ * R_ * 2);
  f16* x0h  = xh1;                     // aliases: dead before xh1 first written
  f16* y0h  = xh1 + (size_t)B_ * H_;

  cvt_f16_kernel<<<(B_ * S_ + 255) / 256, 256, 0, stream>>>(s, sh, B_ * S_);
  dim3 tb(32, 8);
  transpose_cvt_kernel<<<dim3(H_ / 32, S_ / 32, 1),   tb, 0, stream>>>(W_in,   Wint, S_, H_, 1.f);
  transpose_cvt_kernel<<<dim3(H_ / 32, H_ / 32, L_),  tb, 0, stream>>>(W_main, Wmt,  H_, H_, 1.f);
  transpose_cvt_kernel<<<dim3(R_ / 32, H_ / 32, L_ * G_), tb, 0, stream>>>(Wa, Wat, H_, R_, 1.f);
  transpose_cvt_kernel<<<dim3(H_ / 32, R_ / 32, L_ * G_), tb, 0, stream>>>(Wb, Wbt, R_, H_, ADAPT);
  transpose_cvt_kernel<<<dim3(A_ / 32, H_ / 32, 1),   tb, 0, stream>>>(W_out,  Wot,  H_, A_, 1.f);

  // x0 = s @ W_in + b_in  [B, H]
  gemm_f16_kernel<64, 128, 32, 64, EPI_Z1><<<dim3(B_ / 64, H_ / 128, 1), 256, 0, stream>>>(
      sh, S_, 0, Wint, S_, 0, nullptr, 0, nullptr, 0, 0,
      S_ / 32, 0, b_in, 0, nullptr, 0, nullptr, x0h, 0, H_, 0);

  // y0 = x0 @ W_main[0] + b_main[0]  [B, H] (group-invariant: 1/16 the work)
  gemm_f16_kernel<64, 128, 32, 64, EPI_Z1><<<dim3(B_ / 64, H_ / 128, 1), 256, 0, stream>>>(
      x0h, H_, 0, Wmt, H_, 0, nullptr, 0, nullptr, 0, 0,
      H_ / 32, 0, b_main, 0, nullptr, 0, nullptr, y0h, 0, H_, 0);

  // layer-0 z1[g] = x0 @ Wa[0,g] + ba[0,g]
  gemm_f16_kernel<64, 64, 32, 32, EPI_Z1><<<dim3(B_ / 64, 1, G_), 256, 0, stream>>>(
      x0h, H_, 0, Wat, H_, (long long)R_ * H_, nullptr, 0, nullptr, 0, 0,
      H_ / 32, 0, ba, R_, nullptr, 0, nullptr, z1h, (long long)B_ * R_, R_, 0);

  // layer-0 combine: x1 = elu(y0 + z1 @ (0.1*Wb[0,g]) + 0.1*bb[0,g]) -> [G,B,H]
  gemm_f16_kernel<128, 128, 64, 64, EPI_L0><<<dim3(G_ * B_ / 128, H_ / 128, 1), 256, 0, stream>>>(
      nullptr, 0, 0, nullptr, 0, 0, z1h, R_, Wbt, R_, (long long)H_ * R_,
      0, R_ / 32, nullptr, 0, bb, H_, y0h, xh0, 0, H_, B_);

  f16* cur = xh0;
  f16* nxt = xh1;
  for (int l = 1; l < L_; ++l) {
    gemm_f16_kernel<64, 64, 32, 32, EPI_Z1><<<dim3(B_ / 64, 1, G_), 256, 0, stream>>>(
        cur, H_, (long long)B_ * H_,
        Wat + (size_t)l * G_ * R_ * H_, H_, (long long)R_ * H_,
        nullptr, 0, nullptr, 0, 0,
        H_ / 32, 0,
        ba + (size_t)l * G_ * R_, R_, nullptr, 0, nullptr,
        z1h, (long long)B_ * R_, R_, 0);
    // 8-phase 256^2 main GEMM with fused adapter concat-K and ELU epilogue
    gemm8_main_kernel<<<512, 512, 0, stream>>>(
        cur, Wmt + (size_t)l * H_ * H_, z1h, Wbt + (size_t)l * G_ * H_ * R_,
        b_main + (size_t)l * H_, bb + (size_t)l * G_ * H_, nxt);
    f16* t = cur; cur = nxt; nxt = t;
  }

  gemm_f16_kernel<128, 128, 64, 64, EPI_OUT><<<dim3(G_ * B_ / 128, A_ / 128, 1), 256, 0, stream>>>(
      cur, H_, 0, Wot, H_, 0, nullptr, 0, nullptr, 0, 0,
      H_ / 32, 0, b_out, 0, nullptr, 0, nullptr, d_out, 0, A_, 0);
}

// Round 6
// 961.847 us; speedup vs baseline: 1.3090x; 1.3090x over previous
//
#include <hip/hip_runtime.h>
#include <cstdint>
#include <cmath>

typedef _Float16 f16;
typedef _Float16 f16x8 __attribute__((ext_vector_type(8)));
typedef float f32x4 __attribute__((ext_vector_type(4)));

#define DEVI static __device__ __forceinline__

constexpr int B_ = 1024, S_ = 512, H_ = 2048, R_ = 64, G_ = 16, L_ = 4, A_ = 256;
constexpr float ADAPT = 0.1f;

// async global->LDS, 16B per lane. Dest is wave-uniform base + lane*16 (HW).
DEVI void gl_lds16(const void* g, void* l) {
  __builtin_amdgcn_global_load_lds((const __attribute__((address_space(1))) void*)g,
                                   (__attribute__((address_space(3))) void*)l,
                                   16, 0, 0);
}

__global__ void cvt_f16_kernel(const float* __restrict__ src, f16* __restrict__ dst, int n) {
  int i = blockIdx.x * blockDim.x + threadIdx.x;
  if (i < n) dst[i] = (f16)src[i];
}

// src [rows][cols] fp32 -> dst [cols][rows] f16 (×scale), batched over blockIdx.z.
__global__ void transpose_cvt_kernel(const float* __restrict__ src, f16* __restrict__ dst,
                                     int rows, int cols, float scale) {
  src += (size_t)blockIdx.z * rows * cols;
  dst += (size_t)blockIdx.z * rows * cols;
  __shared__ float tile[32][33];
  const int tx = threadIdx.x, ty = threadIdx.y;
  const int r0 = blockIdx.y * 32, c0 = blockIdx.x * 32;
  #pragma unroll
  for (int i = ty; i < 32; i += 8)
    tile[i][tx] = src[(size_t)(r0 + i) * cols + (c0 + tx)];
  __syncthreads();
  #pragma unroll
  for (int i = ty; i < 32; i += 8)
    dst[(size_t)(c0 + i) * rows + (r0 + tx)] = (f16)(tile[tx][i] * scale);
}

// ============================================================================
// 8-phase 256x256 main GEMM. VAR=0: round-4 schedule (same-phase reads,
// single vmcnt(6)/tile). VAR=1: operand-rotation lookahead (reads of phase p
// feed MFMA of p+1; WV8/WV8/WV6 ladder), no sched_barrier pinning.
//   Out = elu( Aacts[16384,2048] @ Wm^T + b1 + Z1[16384,64] @ (0.1*Wb)^T + 0.1*b2 )
// ============================================================================

#define MQ(QM, QN, AF, BF)                                                   \
  _Pragma("unroll") for (int i = 0; i < 4; ++i)                              \
  _Pragma("unroll") for (int j = 0; j < 2; ++j)                              \
  _Pragma("unroll") for (int k = 0; k < 2; ++k)                              \
    acc[QM][QN][i][j] = __builtin_amdgcn_mfma_f32_16x16x32_f16(              \
        AF[i][k], BF[j][k], acc[QM][QN][i][j], 0, 0, 0)

#define STGM(BASE, OFF, DST) do {                                            \
    gl_lds16(BASE + OFF, &lds[DST]);                                         \
    gl_lds16(BASE + OFF + 32768, &lds[DST + 1024]);                          \
    OFF += 128; DST ^= 65536; } while (0)
#define STGC(BASE, OFF, DST) do {                                            \
    gl_lds16(BASE + OFF, &lds[DST]);                                         \
    gl_lds16(BASE + OFF + 1024, &lds[DST + 1024]);                           \
    DST ^= 65536; } while (0)
#define NOSTG ((void)0)
#define WV8 asm volatile("s_waitcnt vmcnt(8)")
#define WV6 asm volatile("s_waitcnt vmcnt(6)")
#define WV4 asm volatile("s_waitcnt vmcnt(4)")
#define WV0 asm volatile("s_waitcnt vmcnt(0)")
#define NOW ((void)0)
#define NORD ((void)0)
#define BAR() __builtin_amdgcn_s_barrier()
#define PRI1 __builtin_amdgcn_s_setprio(1)
#define PRI0 __builtin_amdgcn_s_setprio(0)

// ---- V0: round-4 TILE (same-phase reads, one vmcnt per tile at phase 4) ----
#define TILE_V0(PC, S1, S2, S3, S4, BW) do {                                 \
    f16x8 a0[4][2], a1[4][2], b0[2][2], b1v[2][2];                           \
    _Pragma("unroll") for (int i = 0; i < 4; ++i) {                          \
      a0[i][0] = *(const f16x8*)&lds[(PC) + cab + i * 2048 + lof0];          \
      a0[i][1] = *(const f16x8*)&lds[(PC) + cab + i * 2048 + lof1]; }        \
    _Pragma("unroll") for (int j = 0; j < 2; ++j) {                          \
      b0[j][0] = *(const f16x8*)&lds[(PC) + cbb + j * 2048 + lof0];          \
      b0[j][1] = *(const f16x8*)&lds[(PC) + cbb + j * 2048 + lof1]; }        \
    S1; BAR();                                                               \
    PRI1; MQ(0, 0, a0, b0); PRI0; BAR();                                     \
    _Pragma("unroll") for (int j = 0; j < 2; ++j) {                          \
      b1v[j][0] = *(const f16x8*)&lds[(PC) + cbb + 16384 + j * 2048 + lof0]; \
      b1v[j][1] = *(const f16x8*)&lds[(PC) + cbb + 16384 + j * 2048 + lof1]; } \
    S2; BAR();                                                               \
    PRI1; MQ(0, 1, a0, b1v); PRI0; BAR();                                    \
    _Pragma("unroll") for (int i = 0; i < 4; ++i) {                          \
      a1[i][0] = *(const f16x8*)&lds[(PC) + cab + 16384 + i * 2048 + lof0];  \
      a1[i][1] = *(const f16x8*)&lds[(PC) + cab + 16384 + i * 2048 + lof1]; } \
    S3; BAR();                                                               \
    PRI1; MQ(1, 1, a1, b1v); PRI0; BAR();                                    \
    S4; BAR();                                                               \
    PRI1; MQ(1, 0, a1, b0); PRI0;                                            \
    BW; BAR();                                                               \
  } while (0)

// ---- V1: rotation lookahead (phase-p reads feed phase-p+1 MFMA) ----
#define RD_A0(P) do { _Pragma("unroll") for (int i = 0; i < 4; ++i) {        \
    fa0[i][0] = *(const f16x8*)&lds[(P) + cab + i * 2048 + lof0];            \
    fa0[i][1] = *(const f16x8*)&lds[(P) + cab + i * 2048 + lof1]; } } while (0)
#define RD_A1(P) do { _Pragma("unroll") for (int i = 0; i < 4; ++i) {        \
    fa1[i][0] = *(const f16x8*)&lds[(P) + cab + 16384 + i * 2048 + lof0];    \
    fa1[i][1] = *(const f16x8*)&lds[(P) + cab + 16384 + i * 2048 + lof1]; } } while (0)
#define RD_B0(P) do { _Pragma("unroll") for (int j = 0; j < 2; ++j) {        \
    fb0[j][0] = *(const f16x8*)&lds[(P) + cbb + j * 2048 + lof0];            \
    fb0[j][1] = *(const f16x8*)&lds[(P) + cbb + j * 2048 + lof1]; } } while (0)
#define RD_B1(P) do { _Pragma("unroll") for (int j = 0; j < 2; ++j) {        \
    fb1[j][0] = *(const f16x8*)&lds[(P) + cbb + 16384 + j * 2048 + lof0];    \
    fb1[j][1] = *(const f16x8*)&lds[(P) + cbb + 16384 + j * 2048 + lof1]; } } while (0)

#define TILE_V1(PC, PN, S1, S2, S3, S4, W2, W3, W4, RD3, RD4) do {           \
    RD_B1(PC); S1; BAR();                                                    \
    PRI1; MQ(0, 0, fa0, fb0); PRI0; BAR();                                   \
    RD_A1(PC); S2; W2; BAR();                                                \
    PRI1; MQ(0, 1, fa0, fb1); PRI0; BAR();                                   \
    RD3; S3; W3; BAR();                                                      \
    PRI1; MQ(1, 1, fa1, fb1); PRI0; BAR();                                   \
    S4; BAR();                                                               \
    PRI1; MQ(1, 0, fa1, fb0); PRI0; RD4; W4; BAR();                          \
  } while (0)

template <int VAR>
__global__ __launch_bounds__(512, 2)
void gemm8_main_kernel(const f16* __restrict__ Aacts,   // [16384][2048]
                      const f16* __restrict__ Wm,       // [2048][2048] W_main^T
                      const f16* __restrict__ Z1,       // [16384][64]
                      const f16* __restrict__ Wb2,      // [G][2048][64] 0.1*Wb^T
                      const float* __restrict__ b1,     // [2048]
                      const float* __restrict__ b2,     // [G][2048]
                      f16* __restrict__ Out) {          // [16384][2048]
  __shared__ __align__(16) char lds[131072];
  const int tid = threadIdx.x, lane = tid & 63, wid = tid >> 6;
  // XCD-aware swizzle: 512 blocks, 8 XCDs.
  const int swz = (blockIdx.x & 7) * 64 + (blockIdx.x >> 3);
  const int bm0 = (swz & 63) * 256, bn0 = (swz >> 6) * 256;
  const int g = bm0 >> 10;
  const char* GA = (const char*)Aacts;
  const char* GB = (const char*)Wm;
  const char* GZ = (const char*)Z1;
  const char* GW2 = (const char*)(Wb2 + (size_t)g * H_ * R_);
  const float* b2g = b2 + (size_t)g * H_;

  // staging source permutation (inverse of read swizzle)
  const int srow8 = lane >> 3;
  const int scolb = ((lane & 7) ^ srow8) * 16;
  // fragment read addressing
  const int fr = lane & 15, fq = lane >> 4;
  const uint32_t lof0 = fr * 128 + ((fq * 16) ^ ((fr & 7) << 4));
  const uint32_t lof1 = lof0 ^ 64;

  const uint32_t rA0 = bm0 + wid * 16 + srow8;
  const uint32_t rB0 = bn0 + wid * 16 + srow8;
  uint32_t oA0 = rA0 * 4096 + scolb;
  uint32_t oA1 = oA0 + 128 * 4096;
  uint32_t oB0 = rB0 * 4096 + scolb;
  uint32_t oB1 = oB0 + 128 * 4096;
  uint32_t dA0 = wid * 2048;
  uint32_t dA1 = 16384 + wid * 2048;
  uint32_t dB0 = 32768 + wid * 2048;
  uint32_t dB1 = 49152 + wid * 2048;
  const uint32_t cab = (wid >> 2) * 8192;
  const uint32_t cbb = 32768 + (wid & 3) * 4096;

  f32x4 acc[2][2][4][2] = {};   // [Qm][Qn][i][j]

  // prologue: stage tile0 (A0,B0,A1,B1) + tile1 (A0,B0,A1); retire tile0.
  STGM(GA, oA0, dA0);
  STGM(GB, oB0, dB0);
  STGM(GA, oA1, dA1);
  STGM(GB, oB1, dB1);
  STGM(GA, oA0, dA0);
  STGM(GB, oB0, dB0);
  STGM(GA, oA1, dA1);
  WV6;
  BAR();

  uint32_t oA0c = rA0 * 128 + scolb;
  uint32_t oA1c = oA0c + 128 * 128;
  uint32_t oB0c = rB0 * 128 + scolb;
  uint32_t oB1c = oB0c + 128 * 128;

  if constexpr (VAR == 0) {
    // steady: tiles 0..29
    #pragma unroll 1
    for (int it = 0; it < 15; ++it) {
      TILE_V0(0,
              STGM(GB, oB1, dB1), STGM(GA, oA0, dA0),
              STGM(GB, oB0, dB0), STGM(GA, oA1, dA1), WV6);
      TILE_V0(65536,
              STGM(GB, oB1, dB1), STGM(GA, oA0, dA0),
              STGM(GB, oB0, dB0), STGM(GA, oA1, dA1), WV6);
    }
    // t=30: B1(31) main; A0/B0/A1 of tile 32 = concat (128B rows)
    TILE_V0(0,
            STGM(GB, oB1, dB1), STGC(GZ, oA0c, dA0),
            STGC(GW2, oB0c, dB0), STGC(GZ, oA1c, dA1), WV6);
    // t=31: B1(32) concat; drain all
    TILE_V0(65536,
            STGC(GW2, oB1c, dB1), NOSTG, NOSTG, NOSTG, WV0);
    // t=32: concat compute only
    TILE_V0(0, NOSTG, NOSTG, NOSTG, NOSTG, NOW);
  } else {
    f16x8 fa0[4][2], fa1[4][2], fb0[2][2], fb1[2][2];
    // pre-read tile0's a0/b0 (consumed by first tile's Q1)
    RD_A0(0);
    RD_B0(0);
    #pragma unroll 1
    for (int it = 0; it < 15; ++it) {
      TILE_V1(0, 65536,
              STGM(GB, oB1, dB1), STGM(GA, oA0, dA0),
              STGM(GB, oB0, dB0), STGM(GA, oA1, dA1),
              WV8, WV8, WV6, RD_A0(65536), RD_B0(65536));
      TILE_V1(65536, 0,
              STGM(GB, oB1, dB1), STGM(GA, oA0, dA0),
              STGM(GB, oB0, dB0), STGM(GA, oA1, dA1),
              WV8, WV8, WV6, RD_A0(0), RD_B0(0));
    }
    TILE_V1(0, 65536,
            STGM(GB, oB1, dB1), STGC(GZ, oA0c, dA0),
            STGC(GW2, oB0c, dB0), STGC(GZ, oA1c, dA1),
            WV8, WV8, WV6, RD_A0(65536), RD_B0(65536));
    TILE_V1(65536, 0,
            STGC(GW2, oB1c, dB1), NOSTG, NOSTG, NOSTG,
            WV6, WV4, WV0, RD_A0(0), RD_B0(0));
    TILE_V1(0, 65536, NOSTG, NOSTG, NOSTG, NOSTG, NOW, NOW, NOW, NORD, NORD);
  }

  // epilogue: v = acc + b1[col] + 0.1*b2[col]; ELU; f16 store
  #pragma unroll
  for (int Qn = 0; Qn < 2; ++Qn) {
    #pragma unroll
    for (int j = 0; j < 2; ++j) {
      const int col = bn0 + Qn * 128 + (wid & 3) * 32 + j * 16 + fr;
      const float bb1 = b1[col];
      const float bb2 = ADAPT * b2g[col];
      #pragma unroll
      for (int Qm = 0; Qm < 2; ++Qm) {
        #pragma unroll
        for (int i = 0; i < 4; ++i) {
          #pragma unroll
          for (int r = 0; r < 4; ++r) {
            const int row = bm0 + Qm * 128 + (wid >> 2) * 64 + i * 16 + fq * 4 + r;
            float v = acc[Qm][Qn][i][j][r] + bb1 + bb2;
            v = v > 0.f ? v : expm1f(v);
            Out[(size_t)row * H_ + col] = (f16)v;
          }
        }
      }
    }
  }
}

enum { EPI_Z1 = 0, EPI_MAIN = 1, EPI_OUT = 2, EPI_L0 = 3 };

// m97-structure GEMM for the small/odd-shaped ops.
template <int BM, int BN, int WM, int WN, int EPI>
__global__ __launch_bounds__((BM / WM) * (BN / WN) * 64)
void gemm_f16_kernel(const f16* __restrict__ A, long long lda, long long Az,
                     const f16* __restrict__ Bw, long long ldb, long long Bz,
                     const f16* __restrict__ A2, long long lda2,
                     const f16* __restrict__ B2w, long long ldb2, long long B2z,
                     int NT1, int NT2,
                     const float* __restrict__ bias1, long long b1z,
                     const float* __restrict__ bias2, long long b2z,
                     const f16* __restrict__ addmat,
                     void* __restrict__ outp, long long out_z, long long ldo,
                     int rows_per_group) {
  constexpr int NW = (BM / WM) * (BN / WN);
  constexpr int FM = WM / 16, FN = WN / 16;
  constexpr int RA = BM / (NW * 16), RB = BN / (NW * 16);
  const int tid = threadIdx.x, lane = tid & 63, wid = tid >> 6;
  const int bm0 = blockIdx.x * BM, bn0 = blockIdx.y * BN;
  const int z = blockIdx.z;
  const int gidx = (rows_per_group > 0) ? (bm0 / rows_per_group) : 0;

  __shared__ __align__(16) f16 As[BM * 32];
  __shared__ __align__(16) f16 Bs[BN * 32];

  const int wm0 = (wid / (BN / WN)) * WM;
  const int wn0 = (wid % (BN / WN)) * WN;
  const int srow = wid * 16 + (lane >> 2);
  const int scol = (lane & 3) * 8;
  const int fr = lane & 15, fq = lane >> 4;

  f32x4 acc[FM][FN] = {};

  const f16* arp = &As[(wm0 + fr) * 32 + fq * 8];
  const f16* brp = &Bs[(wn0 + fr) * 32 + fq * 8];
  auto compute = [&]() {
    f16x8 af[FM], bf[FN];
    #pragma unroll
    for (int i = 0; i < FM; ++i) af[i] = *(const f16x8*)(arp + i * 16 * 32);
    #pragma unroll
    for (int j = 0; j < FN; ++j) bf[j] = *(const f16x8*)(brp + j * 16 * 32);
    #pragma unroll
    for (int i = 0; i < FM; ++i)
      #pragma unroll
      for (int j = 0; j < FN; ++j)
        acc[i][j] = __builtin_amdgcn_mfma_f32_16x16x32_f16(af[i], bf[j], acc[i][j], 0, 0, 0);
  };

  if (NT1 > 0) {
    const f16* pa = A + (long long)z * Az + (long long)(bm0 + srow) * lda + scol;
    const f16* pb = Bw + (long long)z * Bz + (long long)(bn0 + srow) * ldb + scol;
    const long long stA = (long long)(NW * 16) * lda;
    const long long stB = (long long)(NW * 16) * ldb;
    for (int kt = 0; kt < NT1; ++kt) {
      #pragma unroll
      for (int r = 0; r < RA; ++r) gl_lds16(pa + r * stA, &As[(r * NW + wid) * 512]);
      #pragma unroll
      for (int r = 0; r < RB; ++r) gl_lds16(pb + r * stB, &Bs[(r * NW + wid) * 512]);
      pa += 32; pb += 32;
      __syncthreads();
      compute();
      __syncthreads();
    }
  }
  if (NT2 > 0) {
    const f16* pa = A2 + (long long)(bm0 + srow) * lda2 + scol;
    const f16* pb = B2w + (long long)gidx * B2z + (long long)(bn0 + srow) * ldb2 + scol;
    const long long stA = (long long)(NW * 16) * lda2;
    const long long stB = (long long)(NW * 16) * ldb2;
    for (int kt = 0; kt < NT2; ++kt) {
      #pragma unroll
      for (int r = 0; r < RA; ++r) gl_lds16(pa + r * stA, &As[(r * NW + wid) * 512]);
      #pragma unroll
      for (int r = 0; r < RB; ++r) gl_lds16(pb + r * stB, &Bs[(r * NW + wid) * 512]);
      pa += 32; pb += 32;
      __syncthreads();
      compute();
      __syncthreads();
    }
  }

  const float* b1p = bias1 ? bias1 + (long long)z * b1z : nullptr;
  const float* b2p = bias2 ? bias2 + (long long)gidx * b2z : nullptr;
  #pragma unroll
  for (int i = 0; i < FM; ++i) {
    #pragma unroll
    for (int j = 0; j < FN; ++j) {
      const int col = bn0 + wn0 + j * 16 + fr;
      const float b1 = b1p ? b1p[col] : 0.f;
      const float b2v = b2p ? ADAPT * b2p[col] : 0.f;
      #pragma unroll
      for (int r = 0; r < 4; ++r) {
        const int row = bm0 + wm0 + i * 16 + fq * 4 + r;
        float v = acc[i][j][r] + b1 + b2v;
        if constexpr (EPI == EPI_MAIN) {
          v = v > 0.f ? v : expm1f(v);
          ((f16*)outp)[(long long)row * ldo + col] = (f16)v;
        } else if constexpr (EPI == EPI_L0) {
          v += (float)addmat[(long long)(row & (B_ - 1)) * H_ + col];
          v = v > 0.f ? v : expm1f(v);
          ((f16*)outp)[(long long)row * ldo + col] = (f16)v;
        } else if constexpr (EPI == EPI_Z1) {
          ((f16*)outp)[(long long)z * out_z + (long long)row * ldo + col] = (f16)v;
        } else {
          const int g = row >> 10, b = row & 1023;
          ((float*)outp)[((long long)b * G_ + g) * A_ + col] = v;
        }
      }
    }
  }
}

extern "C" void kernel_launch(void* const* d_in, const int* in_sizes, int n_in,
                              void* d_out, int out_size, void* d_ws, size_t ws_size,
                              hipStream_t stream) {
  const float* s      = (const float*)d_in[0];
  const float* W_in   = (const float*)d_in[1];
  const float* b_in   = (const float*)d_in[2];
  const float* W_main = (const float*)d_in[3];
  const float* b_main = (const float*)d_in[4];
  const float* Wa     = (const float*)d_in[5];
  const float* ba     = (const float*)d_in[6];
  const float* Wb     = (const float*)d_in[7];
  const float* bb     = (const float*)d_in[8];
  const float* W_out  = (const float*)d_in[9];
  const float* b_out  = (const float*)d_in[10];

  char* ws = (char*)d_ws;
  size_t off = 0;
  auto alloc = [&](size_t bytes) -> void* {
    void* p = ws + off;
    off += (bytes + 255) & ~(size_t)255;
    return p;
  };
  f16* sh   = (f16*)alloc((size_t)B_ * S_ * 2);
  f16* Wint = (f16*)alloc((size_t)H_ * S_ * 2);
  f16* Wmt  = (f16*)alloc((size_t)L_ * H_ * H_ * 2);
  f16* Wat  = (f16*)alloc((size_t)L_ * G_ * R_ * H_ * 2);
  f16* Wbt  = (f16*)alloc((size_t)L_ * G_ * H_ * R_ * 2);
  f16* Wot  = (f16*)alloc((size_t)A_ * H_ * 2);
  f16* xh0  = (f16*)alloc((size_t)G_ * B_ * H_ * 2);
  f16* xh1  = (f16*)alloc((size_t)G_ * B_ * H_ * 2);
  f16* z1h  = (f16*)alloc((size_t)G_ * B_ * R_ * 2);
  f16* x0h  = xh1;                     // aliases: dead before xh1 first written
  f16* y0h  = xh1 + (size_t)B_ * H_;

  cvt_f16_kernel<<<(B_ * S_ + 255) / 256, 256, 0, stream>>>(s, sh, B_ * S_);
  dim3 tb(32, 8);
  transpose_cvt_kernel<<<dim3(H_ / 32, S_ / 32, 1),   tb, 0, stream>>>(W_in,   Wint, S_, H_, 1.f);
  transpose_cvt_kernel<<<dim3(H_ / 32, H_ / 32, L_),  tb, 0, stream>>>(W_main, Wmt,  H_, H_, 1.f);
  transpose_cvt_kernel<<<dim3(R_ / 32, H_ / 32, L_ * G_), tb, 0, stream>>>(Wa, Wat, H_, R_, 1.f);
  transpose_cvt_kernel<<<dim3(H_ / 32, R_ / 32, L_ * G_), tb, 0, stream>>>(Wb, Wbt, R_, H_, ADAPT);
  transpose_cvt_kernel<<<dim3(A_ / 32, H_ / 32, 1),   tb, 0, stream>>>(W_out,  Wot,  H_, A_, 1.f);

  // x0 = s @ W_in + b_in  [B, H]
  gemm_f16_kernel<64, 128, 32, 64, EPI_Z1><<<dim3(B_ / 64, H_ / 128, 1), 256, 0, stream>>>(
      sh, S_, 0, Wint, S_, 0, nullptr, 0, nullptr, 0, 0,
      S_ / 32, 0, b_in, 0, nullptr, 0, nullptr, x0h, 0, H_, 0);

  // y0 = x0 @ W_main[0] + b_main[0]  [B, H] (group-invariant: 1/16 the work)
  gemm_f16_kernel<64, 128, 32, 64, EPI_Z1><<<dim3(B_ / 64, H_ / 128, 1), 256, 0, stream>>>(
      x0h, H_, 0, Wmt, H_, 0, nullptr, 0, nullptr, 0, 0,
      H_ / 32, 0, b_main, 0, nullptr, 0, nullptr, y0h, 0, H_, 0);

  // layer-0 z1[g] = x0 @ Wa[0,g] + ba[0,g]
  gemm_f16_kernel<64, 64, 32, 32, EPI_Z1><<<dim3(B_ / 64, 1, G_), 256, 0, stream>>>(
      x0h, H_, 0, Wat, H_, (long long)R_ * H_, nullptr, 0, nullptr, 0, 0,
      H_ / 32, 0, ba, R_, nullptr, 0, nullptr, z1h, (long long)B_ * R_, R_, 0);

  // layer-0 combine: x1 = elu(y0 + z1 @ (0.1*Wb[0,g]) + 0.1*bb[0,g]) -> [G,B,H]
  gemm_f16_kernel<128, 128, 64, 64, EPI_L0><<<dim3(G_ * B_ / 128, H_ / 128, 1), 256, 0, stream>>>(
      nullptr, 0, 0, nullptr, 0, 0, z1h, R_, Wbt, R_, (long long)H_ * R_,
      0, R_ / 32, nullptr, 0, bb, H_, y0h, xh0, 0, H_, B_);

  f16* cur = xh0;
  f16* nxt = xh1;
  for (int l = 1; l < L_; ++l) {
    gemm_f16_kernel<64, 64, 32, 32, EPI_Z1><<<dim3(B_ / 64, 1, G_), 256, 0, stream>>>(
        cur, H_, (long long)B_ * H_,
        Wat + (size_t)l * G_ * R_ * H_, H_, (long long)R_ * H_,
        nullptr, 0, nullptr, 0, 0,
        H_ / 32, 0,
        ba + (size_t)l * G_ * R_, R_, nullptr, 0, nullptr,
        z1h, (long long)B_ * R_, R_, 0);
    // A/B: layers 1,3 -> V0 (round-4 schedule); layer 2 -> V1 (rotation)
    if (l == 2)
      gemm8_main_kernel<1><<<512, 512, 0, stream>>>(
          cur, Wmt + (size_t)l * H_ * H_, z1h, Wbt + (size_t)l * G_ * H_ * R_,
          b_main + (size_t)l * H_, bb + (size_t)l * G_ * H_, nxt);
    else
      gemm8_main_kernel<0><<<512, 512, 0, stream>>>(
          cur, Wmt + (size_t)l * H_ * H_, z1h, Wbt + (size_t)l * G_ * H_ * R_,
          b_main + (size_t)l * H_, bb + (size_t)l * G_ * H_, nxt);
    f16* t = cur; cur = nxt; nxt = t;
  }

  gemm_f16_kernel<128, 128, 64, 64, EPI_OUT><<<dim3(G_ * B_ / 128, A_ / 128, 1), 256, 0, stream>>>(
      cur, H_, 0, Wot, H_, 0, nullptr, 0, nullptr, 0, 0,
      H_ / 32, 0, b_out, 0, nullptr, 0, nullptr, d_out, 0, A_, 0);
}

// Round 7
// 760.495 us; speedup vs baseline: 1.6555x; 1.2648x over previous
//
#include <hip/hip_runtime.h>
#include <cstdint>
#include <cmath>

typedef _Float16 f16;
typedef _Float16 f16x8 __attribute__((ext_vector_type(8)));
typedef float f32x4 __attribute__((ext_vector_type(4)));

#define DEVI static __device__ __forceinline__

constexpr int B_ = 1024, S_ = 512, H_ = 2048, R_ = 64, G_ = 16, L_ = 4, A_ = 256;
constexpr float ADAPT = 0.1f;

// async global->LDS, 16B per lane. Dest is wave-uniform base + lane*16 (HW).
DEVI void gl_lds16(const void* g, void* l) {
  __builtin_amdgcn_global_load_lds((const __attribute__((address_space(1))) void*)g,
                                   (__attribute__((address_space(3))) void*)l,
                                   16, 0, 0);
}

template <int N> DEVI void wvc() {
  if constexpr (N == 0)       asm volatile("s_waitcnt vmcnt(0)");
  else if constexpr (N == 2)  asm volatile("s_waitcnt vmcnt(2)");
  else if constexpr (N == 3)  asm volatile("s_waitcnt vmcnt(3)");
  else if constexpr (N == 4)  asm volatile("s_waitcnt vmcnt(4)");
  else if constexpr (N == 6)  asm volatile("s_waitcnt vmcnt(6)");
  else if constexpr (N == 8)  asm volatile("s_waitcnt vmcnt(8)");
  else if constexpr (N == 9)  asm volatile("s_waitcnt vmcnt(9)");
  else if constexpr (N == 12) asm volatile("s_waitcnt vmcnt(12)");
  else static_assert(N == 0, "unsupported vmcnt literal");
}

__global__ void cvt_f16_kernel(const float* __restrict__ src, f16* __restrict__ dst, int n) {
  int i = blockIdx.x * blockDim.x + threadIdx.x;
  if (i < n) dst[i] = (f16)src[i];
}

// src [rows][cols] fp32 -> dst [cols][rows] f16 (×scale), batched over blockIdx.z.
__global__ void transpose_cvt_kernel(const float* __restrict__ src, f16* __restrict__ dst,
                                     int rows, int cols, float scale) {
  src += (size_t)blockIdx.z * rows * cols;
  dst += (size_t)blockIdx.z * rows * cols;
  __shared__ float tile[32][33];
  const int tx = threadIdx.x, ty = threadIdx.y;
  const int r0 = blockIdx.y * 32, c0 = blockIdx.x * 32;
  #pragma unroll
  for (int i = ty; i < 32; i += 8)
    tile[i][tx] = src[(size_t)(r0 + i) * cols + (c0 + tx)];
  __syncthreads();
  #pragma unroll
  for (int i = ty; i < 32; i += 8)
    dst[(size_t)(c0 + i) * rows + (r0 + tx)] = (f16)(tile[tx][i] * scale);
}

// ============================================================================
// Main 256x256 8-phase GEMM — round-4 V0 schedule exactly (best measured:
// 161 us, 843 TF). Same-phase reads + compiler-counted lgkm; vmcnt(6)/tile.
//   Out = elu( Aacts[16384,2048] @ Wm^T + b1 + Z1[16384,64] @ (0.1*Wb)^T + 0.1*b2 )
// ============================================================================

#define MQ(QM, QN, AF, BF)                                                   \
  _Pragma("unroll") for (int i = 0; i < 4; ++i)                              \
  _Pragma("unroll") for (int j = 0; j < 2; ++j)                              \
  _Pragma("unroll") for (int k = 0; k < 2; ++k)                              \
    acc[QM][QN][i][j] = __builtin_amdgcn_mfma_f32_16x16x32_f16(              \
        AF[i][k], BF[j][k], acc[QM][QN][i][j], 0, 0, 0)

#define STGM(BASE, OFF, DST) do {                                            \
    gl_lds16(BASE + OFF, &lds[DST]);                                         \
    gl_lds16(BASE + OFF + 32768, &lds[DST + 1024]);                          \
    OFF += 128; DST ^= 65536; } while (0)
#define STGC(BASE, OFF, DST) do {                                            \
    gl_lds16(BASE + OFF, &lds[DST]);                                         \
    gl_lds16(BASE + OFF + 1024, &lds[DST + 1024]);                           \
    DST ^= 65536; } while (0)
#define NOSTG ((void)0)
#define WV6 asm volatile("s_waitcnt vmcnt(6)")
#define WV0 asm volatile("s_waitcnt vmcnt(0)")
#define NOW ((void)0)
#define BAR() __builtin_amdgcn_s_barrier()
#define PRI1 __builtin_amdgcn_s_setprio(1)
#define PRI0 __builtin_amdgcn_s_setprio(0)

#define TILE_V0(PC, S1, S2, S3, S4, BW) do {                                 \
    f16x8 a0[4][2], a1[4][2], b0[2][2], b1v[2][2];                           \
    _Pragma("unroll") for (int i = 0; i < 4; ++i) {                          \
      a0[i][0] = *(const f16x8*)&lds[(PC) + cab + i * 2048 + lof0];          \
      a0[i][1] = *(const f16x8*)&lds[(PC) + cab + i * 2048 + lof1]; }        \
    _Pragma("unroll") for (int j = 0; j < 2; ++j) {                          \
      b0[j][0] = *(const f16x8*)&lds[(PC) + cbb + j * 2048 + lof0];          \
      b0[j][1] = *(const f16x8*)&lds[(PC) + cbb + j * 2048 + lof1]; }        \
    S1; BAR();                                                               \
    PRI1; MQ(0, 0, a0, b0); PRI0; BAR();                                     \
    _Pragma("unroll") for (int j = 0; j < 2; ++j) {                          \
      b1v[j][0] = *(const f16x8*)&lds[(PC) + cbb + 16384 + j * 2048 + lof0]; \
      b1v[j][1] = *(const f16x8*)&lds[(PC) + cbb + 16384 + j * 2048 + lof1]; } \
    S2; BAR();                                                               \
    PRI1; MQ(0, 1, a0, b1v); PRI0; BAR();                                    \
    _Pragma("unroll") for (int i = 0; i < 4; ++i) {                          \
      a1[i][0] = *(const f16x8*)&lds[(PC) + cab + 16384 + i * 2048 + lof0];  \
      a1[i][1] = *(const f16x8*)&lds[(PC) + cab + 16384 + i * 2048 + lof1]; } \
    S3; BAR();                                                               \
    PRI1; MQ(1, 1, a1, b1v); PRI0; BAR();                                    \
    S4; BAR();                                                               \
    PRI1; MQ(1, 0, a1, b0); PRI0;                                            \
    BW; BAR();                                                               \
  } while (0)

__global__ __launch_bounds__(512, 2)
void gemm8_main_kernel(const f16* __restrict__ Aacts,   // [16384][2048]
                      const f16* __restrict__ Wm,       // [2048][2048] W_main^T
                      const f16* __restrict__ Z1,       // [16384][64]
                      const f16* __restrict__ Wb2,      // [G][2048][64] 0.1*Wb^T
                      const float* __restrict__ b1,     // [2048]
                      const float* __restrict__ b2,     // [G][2048]
                      f16* __restrict__ Out) {          // [16384][2048]
  __shared__ __align__(16) char lds[131072];
  const int tid = threadIdx.x, lane = tid & 63, wid = tid >> 6;
  // XCD-aware swizzle: 512 blocks, 8 XCDs.
  const int swz = (blockIdx.x & 7) * 64 + (blockIdx.x >> 3);
  const int bm0 = (swz & 63) * 256, bn0 = (swz >> 6) * 256;
  const int g = bm0 >> 10;
  const char* GA = (const char*)Aacts;
  const char* GB = (const char*)Wm;
  const char* GZ = (const char*)Z1;
  const char* GW2 = (const char*)(Wb2 + (size_t)g * H_ * R_);
  const float* b2g = b2 + (size_t)g * H_;

  // staging source permutation (inverse of read swizzle)
  const int srow8 = lane >> 3;
  const int scolb = ((lane & 7) ^ srow8) * 16;
  // fragment read addressing
  const int fr = lane & 15, fq = lane >> 4;
  const uint32_t lof0 = fr * 128 + ((fq * 16) ^ ((fr & 7) << 4));
  const uint32_t lof1 = lof0 ^ 64;

  const uint32_t rA0 = bm0 + wid * 16 + srow8;
  const uint32_t rB0 = bn0 + wid * 16 + srow8;
  uint32_t oA0 = rA0 * 4096 + scolb;
  uint32_t oA1 = oA0 + 128 * 4096;
  uint32_t oB0 = rB0 * 4096 + scolb;
  uint32_t oB1 = oB0 + 128 * 4096;
  uint32_t dA0 = wid * 2048;
  uint32_t dA1 = 16384 + wid * 2048;
  uint32_t dB0 = 32768 + wid * 2048;
  uint32_t dB1 = 49152 + wid * 2048;
  const uint32_t cab = (wid >> 2) * 8192;
  const uint32_t cbb = 32768 + (wid & 3) * 4096;

  f32x4 acc[2][2][4][2] = {};   // [Qm][Qn][i][j]

  // prologue: stage tile0 (A0,B0,A1,B1) + tile1 (A0,B0,A1); retire tile0.
  STGM(GA, oA0, dA0);
  STGM(GB, oB0, dB0);
  STGM(GA, oA1, dA1);
  STGM(GB, oB1, dB1);
  STGM(GA, oA0, dA0);
  STGM(GB, oB0, dB0);
  STGM(GA, oA1, dA1);
  WV6;
  BAR();

  uint32_t oA0c = rA0 * 128 + scolb;
  uint32_t oA1c = oA0c + 128 * 128;
  uint32_t oB0c = rB0 * 128 + scolb;
  uint32_t oB1c = oB0c + 128 * 128;

  // steady: tiles 0..29
  #pragma unroll 1
  for (int it = 0; it < 15; ++it) {
    TILE_V0(0,
            STGM(GB, oB1, dB1), STGM(GA, oA0, dA0),
            STGM(GB, oB0, dB0), STGM(GA, oA1, dA1), WV6);
    TILE_V0(65536,
            STGM(GB, oB1, dB1), STGM(GA, oA0, dA0),
            STGM(GB, oB0, dB0), STGM(GA, oA1, dA1), WV6);
  }
  // t=30: B1(31) main; A0/B0/A1 of tile 32 = concat (128B rows)
  TILE_V0(0,
          STGM(GB, oB1, dB1), STGC(GZ, oA0c, dA0),
          STGC(GW2, oB0c, dB0), STGC(GZ, oA1c, dA1), WV6);
  // t=31: B1(32) concat; drain all
  TILE_V0(65536,
          STGC(GW2, oB1c, dB1), NOSTG, NOSTG, NOSTG, WV0);
  // t=32: concat compute only
  TILE_V0(0, NOSTG, NOSTG, NOSTG, NOSTG, NOW);

  // epilogue: v = acc + b1[col] + 0.1*b2[col]; ELU; f16 store
  #pragma unroll
  for (int Qn = 0; Qn < 2; ++Qn) {
    #pragma unroll
    for (int j = 0; j < 2; ++j) {
      const int col = bn0 + Qn * 128 + (wid & 3) * 32 + j * 16 + fr;
      const float bb1 = b1[col];
      const float bb2 = ADAPT * b2g[col];
      #pragma unroll
      for (int Qm = 0; Qm < 2; ++Qm) {
        #pragma unroll
        for (int i = 0; i < 4; ++i) {
          #pragma unroll
          for (int r = 0; r < 4; ++r) {
            const int row = bm0 + Qm * 128 + (wid >> 2) * 64 + i * 16 + fq * 4 + r;
            float v = acc[Qm][Qn][i][j][r] + bb1 + bb2;
            v = v > 0.f ? v : expm1f(v);
            Out[(size_t)row * H_ + col] = (f16)v;
          }
        }
      }
    }
  }
}

enum { EPI_Z1 = 0, EPI_OUT = 1, EPI_L0 = 2 };

// ============================================================================
// Small/odd-shape GEMM with 4-deep ring-buffer pipeline (counted vmcnt,
// raw barriers) replacing the 2-barrier __syncthreads loop. BK=32.
// out[M,N] = A[M,K] * Bw^T (Bw stored [N][K]); z-batch + group-offset on B.
// ============================================================================
template <int BM, int BN, int WM, int WN, int EPI>
__global__ __launch_bounds__((BM / WM) * (BN / WN) * 64)
void gemm_db_kernel(const f16* __restrict__ A, long long lda, long long Az,
                    const f16* __restrict__ Bw, long long ldb, long long Bz,
                    long long Bg, int NT,
                    const float* __restrict__ bias1, long long b1z,
                    const float* __restrict__ bias2, long long b2z,
                    const f16* __restrict__ addmat,
                    void* __restrict__ outp, long long out_z, long long ldo,
                    int rows_per_group) {
  constexpr int NW = (BM / WM) * (BN / WN);
  constexpr int FM = WM / 16, FN = WN / 16;
  constexpr int RA = BM / (NW * 16), RB = BN / (NW * 16);
  constexpr int LPT = RA + RB;   // gl_lds per thread per tile
  const int tid = threadIdx.x, lane = tid & 63, wid = tid >> 6;
  const int bm0 = blockIdx.x * BM, bn0 = blockIdx.y * BN;
  const int z = blockIdx.z;
  const int gidx = (rows_per_group > 0) ? (bm0 / rows_per_group) : 0;

  __shared__ __align__(16) f16 As[4][BM * 32];
  __shared__ __align__(16) f16 Bs[4][BN * 32];

  const int wm0 = (wid / (BN / WN)) * WM;
  const int wn0 = (wid % (BN / WN)) * WN;
  const int srow = wid * 16 + (lane >> 2);
  const int scol = (lane & 3) * 8;
  const int fr = lane & 15, fq = lane >> 4;

  const f16* pa = A + (long long)z * Az + (long long)(bm0 + srow) * lda + scol;
  const f16* pb = Bw + (long long)z * Bz + (long long)gidx * Bg +
                  (long long)(bn0 + srow) * ldb + scol;
  const long long stA = (long long)(NW * 16) * lda;
  const long long stB = (long long)(NW * 16) * ldb;

  f32x4 acc[FM][FN] = {};

  auto stage = [&](int t) {
    const f16* qa = pa + t * 32;
    const f16* qb = pb + t * 32;
    const int b = t & 3;
    #pragma unroll
    for (int r = 0; r < RA; ++r)
      gl_lds16(qa + r * stA, &As[b][(r * NW + wid) * 512]);
    #pragma unroll
    for (int r = 0; r < RB; ++r)
      gl_lds16(qb + r * stB, &Bs[b][(r * NW + wid) * 512]);
  };
  auto comp = [&](int t) {
    const int b = t & 3;
    f16x8 af[FM], bf[FN];
    #pragma unroll
    for (int i = 0; i < FM; ++i)
      af[i] = *(const f16x8*)&As[b][(wm0 + i * 16 + fr) * 32 + fq * 8];
    #pragma unroll
    for (int j = 0; j < FN; ++j)
      bf[j] = *(const f16x8*)&Bs[b][(wn0 + j * 16 + fr) * 32 + fq * 8];
    #pragma unroll
    for (int i = 0; i < FM; ++i)
      #pragma unroll
      for (int j = 0; j < FN; ++j)
        acc[i][j] = __builtin_amdgcn_mfma_f32_16x16x32_f16(af[i], bf[j], acc[i][j], 0, 0, 0);
  };

  if (NT <= 4) {
    // short-K path (L0 combine): stage all, drain, compute.
    for (int t = 0; t < NT; ++t) stage(t);
    wvc<0>();
    BAR();
    for (int t = 0; t < NT; ++t) comp(t);
  } else {
    stage(0); stage(1); stage(2); stage(3);
    int t = 0;
    #pragma unroll 1
    for (; t < NT - 4; ++t) {
      wvc<3 * LPT>();   // tile t landed (<=3 tile-groups outstanding)
      BAR();
      comp(t);
      BAR();            // all waves done reading buf[t&3]
      stage(t + 4);     // overwrite it
    }
    wvc<3 * LPT>(); BAR(); comp(t); BAR(); ++t;
    wvc<2 * LPT>(); BAR(); comp(t); BAR(); ++t;
    wvc<1 * LPT>(); BAR(); comp(t); BAR(); ++t;
    wvc<0>();       BAR(); comp(t);
  }

  // epilogue (C/D layout: col = lane&15, row = (lane>>4)*4 + r)
  const float* b1p = bias1 ? bias1 + (long long)z * b1z : nullptr;
  const float* b2p = bias2 ? bias2 + (long long)gidx * b2z : nullptr;
  #pragma unroll
  for (int i = 0; i < FM; ++i) {
    #pragma unroll
    for (int j = 0; j < FN; ++j) {
      const int col = bn0 + wn0 + j * 16 + fr;
      const float b1 = b1p ? b1p[col] : 0.f;
      const float b2v = b2p ? ADAPT * b2p[col] : 0.f;
      #pragma unroll
      for (int r = 0; r < 4; ++r) {
        const int row = bm0 + wm0 + i * 16 + fq * 4 + r;
        float v = acc[i][j][r] + b1 + b2v;
        if constexpr (EPI == EPI_L0) {
          v += (float)addmat[(long long)(row & (B_ - 1)) * H_ + col];
          v = v > 0.f ? v : expm1f(v);
          ((f16*)outp)[(long long)row * ldo + col] = (f16)v;
        } else if constexpr (EPI == EPI_Z1) {
          ((f16*)outp)[(long long)z * out_z + (long long)row * ldo + col] = (f16)v;
        } else {  // EPI_OUT: group-major row -> [B, G, A] fp32
          const int g = row >> 10, b = row & 1023;
          ((float*)outp)[((long long)b * G_ + g) * A_ + col] = v;
        }
      }
    }
  }
}

extern "C" void kernel_launch(void* const* d_in, const int* in_sizes, int n_in,
                              void* d_out, int out_size, void* d_ws, size_t ws_size,
                              hipStream_t stream) {
  const float* s      = (const float*)d_in[0];
  const float* W_in   = (const float*)d_in[1];
  const float* b_in   = (const float*)d_in[2];
  const float* W_main = (const float*)d_in[3];
  const float* b_main = (const float*)d_in[4];
  const float* Wa     = (const float*)d_in[5];
  const float* ba     = (const float*)d_in[6];
  const float* Wb     = (const float*)d_in[7];
  const float* bb     = (const float*)d_in[8];
  const float* W_out  = (const float*)d_in[9];
  const float* b_out  = (const float*)d_in[10];

  char* ws = (char*)d_ws;
  size_t off = 0;
  auto alloc = [&](size_t bytes) -> void* {
    void* p = ws + off;
    off += (bytes + 255) & ~(size_t)255;
    return p;
  };
  f16* sh   = (f16*)alloc((size_t)B_ * S_ * 2);
  f16* Wint = (f16*)alloc((size_t)H_ * S_ * 2);
  f16* Wmt  = (f16*)alloc((size_t)L_ * H_ * H_ * 2);
  f16* Wat  = (f16*)alloc((size_t)L_ * G_ * R_ * H_ * 2);
  f16* Wbt  = (f16*)alloc((size_t)L_ * G_ * H_ * R_ * 2);
  f16* Wot  = (f16*)alloc((size_t)A_ * H_ * 2);
  f16* xh0  = (f16*)alloc((size_t)G_ * B_ * H_ * 2);
  f16* xh1  = (f16*)alloc((size_t)G_ * B_ * H_ * 2);
  f16* z1h  = (f16*)alloc((size_t)G_ * B_ * R_ * 2);
  f16* x0h  = xh1;                     // aliases: dead before xh1 first written
  f16* y0h  = xh1 + (size_t)B_ * H_;

  cvt_f16_kernel<<<(B_ * S_ + 255) / 256, 256, 0, stream>>>(s, sh, B_ * S_);
  dim3 tb(32, 8);
  transpose_cvt_kernel<<<dim3(H_ / 32, S_ / 32, 1),   tb, 0, stream>>>(W_in,   Wint, S_, H_, 1.f);
  transpose_cvt_kernel<<<dim3(H_ / 32, H_ / 32, L_),  tb, 0, stream>>>(W_main, Wmt,  H_, H_, 1.f);
  transpose_cvt_kernel<<<dim3(R_ / 32, H_ / 32, L_ * G_), tb, 0, stream>>>(Wa, Wat, H_, R_, 1.f);
  transpose_cvt_kernel<<<dim3(H_ / 32, R_ / 32, L_ * G_), tb, 0, stream>>>(Wb, Wbt, R_, H_, ADAPT);
  transpose_cvt_kernel<<<dim3(A_ / 32, H_ / 32, 1),   tb, 0, stream>>>(W_out,  Wot,  H_, A_, 1.f);

  // x0 = s @ W_in + b_in  [B, H]
  gemm_db_kernel<64, 128, 32, 64, EPI_Z1><<<dim3(B_ / 64, H_ / 128, 1), 256, 0, stream>>>(
      sh, S_, 0, Wint, S_, 0, 0, S_ / 32,
      b_in, 0, nullptr, 0, nullptr, x0h, 0, H_, 0);

  // y0 = x0 @ W_main[0] + b_main[0]  [B, H] (group-invariant: 1/16 the work)
  gemm_db_kernel<64, 128, 32, 64, EPI_Z1><<<dim3(B_ / 64, H_ / 128, 1), 256, 0, stream>>>(
      x0h, H_, 0, Wmt, H_, 0, 0, H_ / 32,
      b_main, 0, nullptr, 0, nullptr, y0h, 0, H_, 0);

  // layer-0 z1[g] = x0 @ Wa[0,g] + ba[0,g]  (Az=0: shared x0)
  gemm_db_kernel<64, 64, 32, 32, EPI_Z1><<<dim3(B_ / 64, 1, G_), 256, 0, stream>>>(
      x0h, H_, 0, Wat, H_, (long long)R_ * H_, 0, H_ / 32,
      ba, R_, nullptr, 0, nullptr, z1h, (long long)B_ * R_, R_, 0);

  // layer-0 combine: x1 = elu(y0 + z1 @ (0.1*Wb[0,g]) + 0.1*bb[0,g]) -> [G,B,H]
  gemm_db_kernel<128, 128, 64, 64, EPI_L0><<<dim3(G_ * B_ / 128, H_ / 128, 1), 256, 0, stream>>>(
      z1h, R_, 0, Wbt, R_, 0, (long long)H_ * R_, R_ / 32,
      nullptr, 0, bb, H_, y0h, xh0, 0, H_, B_);

  f16* cur = xh0;
  f16* nxt = xh1;
  for (int l = 1; l < L_; ++l) {
    gemm_db_kernel<64, 64, 32, 32, EPI_Z1><<<dim3(B_ / 64, 1, G_), 256, 0, stream>>>(
        cur, H_, (long long)B_ * H_,
        Wat + (size_t)l * G_ * R_ * H_, H_, (long long)R_ * H_, 0, H_ / 32,
        ba + (size_t)l * G_ * R_, R_, nullptr, 0, nullptr,
        z1h, (long long)B_ * R_, R_, 0);
    // 8-phase 256^2 main GEMM (V0) with fused adapter concat-K and ELU epilogue
    gemm8_main_kernel<<<512, 512, 0, stream>>>(
        cur, Wmt + (size_t)l * H_ * H_, z1h, Wbt + (size_t)l * G_ * H_ * R_,
        b_main + (size_t)l * H_, bb + (size_t)l * G_ * H_, nxt);
    f16* t = cur; cur = nxt; nxt = t;
  }

  // output: logits[b,g,:] = x @ W_out + b_out (fp32, permuted store)
  gemm_db_kernel<128, 128, 64, 64, EPI_OUT><<<dim3(G_ * B_ / 128, A_ / 128, 1), 256, 0, stream>>>(
      cur, H_, 0, Wot, H_, 0, 0, H_ / 32,
      b_out, 0, nullptr, 0, nullptr, d_out, 0, A_, 0);
}

// Round 9
// 743.401 us; speedup vs baseline: 1.6936x; 1.0230x over previous
//
#include <hip/hip_runtime.h>
#include <cstdint>
#include <cmath>

typedef _Float16 f16;
typedef _Float16 f16x8 __attribute__((ext_vector_type(8)));
typedef float f32x4 __attribute__((ext_vector_type(4)));

#define DEVI static __device__ __forceinline__

constexpr int B_ = 1024, S_ = 512, H_ = 2048, R_ = 64, G_ = 16, L_ = 4, A_ = 256;
constexpr float ADAPT = 0.1f;

// async global->LDS, 16B per lane. Dest is wave-uniform base + lane*16 (HW).
DEVI void gl_lds16(const void* g, void* l) {
  __builtin_amdgcn_global_load_lds((const __attribute__((address_space(1))) void*)g,
                                   (__attribute__((address_space(3))) void*)l,
                                   16, 0, 0);
}

template <int N> DEVI void wvc() {
  if constexpr (N == 0)       asm volatile("s_waitcnt vmcnt(0)");
  else if constexpr (N == 1)  asm volatile("s_waitcnt vmcnt(1)");
  else if constexpr (N == 2)  asm volatile("s_waitcnt vmcnt(2)");
  else if constexpr (N == 3)  asm volatile("s_waitcnt vmcnt(3)");
  else if constexpr (N == 4)  asm volatile("s_waitcnt vmcnt(4)");
  else if constexpr (N == 6)  asm volatile("s_waitcnt vmcnt(6)");
  else if constexpr (N == 8)  asm volatile("s_waitcnt vmcnt(8)");
  else if constexpr (N == 9)  asm volatile("s_waitcnt vmcnt(9)");
  else if constexpr (N == 12) asm volatile("s_waitcnt vmcnt(12)");
  else static_assert(N == 0, "unsupported vmcnt literal");
}

// ============================================================================
// prep_kernel: all input conversions in ONE launch.
// segments: [0,2048) cvt s | [.. +1024) W_in^T | [+16384) W_main^T |
//           [+8192) Wa^T | [+8192) 0.1*Wb^T | [+512) W_out^T
// ============================================================================
DEVI void tr_body(float (*tile)[33], const float* __restrict__ src, f16* __restrict__ dst,
                  int rows, int cols, float scale, int bid) {
  const int nx = cols / 32, ny = rows / 32;
  const int z = bid / (nx * ny), rem = bid % (nx * ny);
  const int cy = rem / nx, cx = rem % nx;
  src += (size_t)z * rows * cols;
  dst += (size_t)z * rows * cols;
  const int tx = threadIdx.x, ty = threadIdx.y;
  const int r0 = cy * 32, c0 = cx * 32;
  #pragma unroll
  for (int i = ty; i < 32; i += 8)
    tile[i][tx] = src[(size_t)(r0 + i) * cols + (c0 + tx)];
  __syncthreads();
  #pragma unroll
  for (int i = ty; i < 32; i += 8)
    dst[(size_t)(c0 + i) * rows + (r0 + tx)] = (f16)(tile[tx][i] * scale);
}

__global__ void prep_kernel(const float* __restrict__ s, f16* __restrict__ sh,
                            const float* __restrict__ W_in, f16* __restrict__ Wint,
                            const float* __restrict__ W_main, f16* __restrict__ Wmt,
                            const float* __restrict__ Wa, f16* __restrict__ Wat,
                            const float* __restrict__ Wb, f16* __restrict__ Wbt,
                            const float* __restrict__ W_out, f16* __restrict__ Wot) {
  __shared__ float tile[32][33];
  int bid = blockIdx.x;
  if (bid < 2048) {               // cvt s: 1024*512 = 2048*256
    int i = bid * 256 + threadIdx.y * 32 + threadIdx.x;
    sh[i] = (f16)s[i];
    return;
  }
  bid -= 2048;
  if (bid < 1024)  { tr_body(tile, W_in,   Wint, S_, H_, 1.f,   bid); return; }
  bid -= 1024;
  if (bid < 16384) { tr_body(tile, W_main, Wmt,  H_, H_, 1.f,   bid); return; }
  bid -= 16384;
  if (bid < 8192)  { tr_body(tile, Wa,     Wat,  H_, R_, 1.f,   bid); return; }
  bid -= 8192;
  if (bid < 8192)  { tr_body(tile, Wb,     Wbt,  R_, H_, ADAPT, bid); return; }
  bid -= 8192;
  tr_body(tile, W_out, Wot, H_, A_, 1.f, bid);
}

// ============================================================================
// Main 256x256 GEMM — 3-phase tile (6 barriers, 32-MFMA final burst).
//   Out = elu( Aacts[16384,2048] @ Wm^T + b1 + Z1[16384,64] @ (0.1*Wb)^T + 0.1*b2 )
// Stage discipline: stage into a region only after a barrier that postdates
// completion of that region's reads.
//   t.P1: B1(t+1), A1(t+1)  [other parity; prior reads finished tiles ago]
//   t.P2: A0(t+2), B0(t+2)  [same parity; a0/b0(t) reads completed pre post-Q1 bar]
// vmcnt: 12 in flight after P2; WV4 at tile end retires tile t+1's 8 loads.
// ============================================================================

#define MQ(QM, QN, AF, BF)                                                   \
  _Pragma("unroll") for (int i = 0; i < 4; ++i)                              \
  _Pragma("unroll") for (int j = 0; j < 2; ++j)                              \
  _Pragma("unroll") for (int k = 0; k < 2; ++k)                              \
    acc[QM][QN][i][j] = __builtin_amdgcn_mfma_f32_16x16x32_f16(              \
        AF[i][k], BF[j][k], acc[QM][QN][i][j], 0, 0, 0)

#define STGM(BASE, OFF, DST) do {                                            \
    gl_lds16(BASE + OFF, &lds[DST]);                                         \
    gl_lds16(BASE + OFF + 32768, &lds[DST + 1024]);                          \
    OFF += 128; DST ^= 65536; } while (0)
#define STGC(BASE, OFF, DST) do {                                            \
    gl_lds16(BASE + OFF, &lds[DST]);                                         \
    gl_lds16(BASE + OFF + 1024, &lds[DST + 1024]);                           \
    DST ^= 65536; } while (0)
#define NOSTG ((void)0)
#define WV4 asm volatile("s_waitcnt vmcnt(4)")
#define WV0 asm volatile("s_waitcnt vmcnt(0)")
#define NOW ((void)0)
#define BAR() __builtin_amdgcn_s_barrier()
#define PRI1 __builtin_amdgcn_s_setprio(1)
#define PRI0 __builtin_amdgcn_s_setprio(0)

#define TILE3(PC, S1a, S1b, S2a, S2b, BW) do {                               \
    f16x8 a0[4][2], a1[4][2], b0[2][2], b1v[2][2];                           \
    _Pragma("unroll") for (int i = 0; i < 4; ++i) {                          \
      a0[i][0] = *(const f16x8*)&lds[(PC) + cab + i * 2048 + lof0];          \
      a0[i][1] = *(const f16x8*)&lds[(PC) + cab + i * 2048 + lof1]; }        \
    _Pragma("unroll") for (int j = 0; j < 2; ++j) {                          \
      b0[j][0] = *(const f16x8*)&lds[(PC) + cbb + j * 2048 + lof0];          \
      b0[j][1] = *(const f16x8*)&lds[(PC) + cbb + j * 2048 + lof1]; }        \
    S1a; S1b; BAR();                                                         \
    PRI1; MQ(0, 0, a0, b0); PRI0; BAR();                                     \
    _Pragma("unroll") for (int j = 0; j < 2; ++j) {                          \
      b1v[j][0] = *(const f16x8*)&lds[(PC) + cbb + 16384 + j * 2048 + lof0]; \
      b1v[j][1] = *(const f16x8*)&lds[(PC) + cbb + 16384 + j * 2048 + lof1]; } \
    S2a; S2b; BAR();                                                         \
    PRI1; MQ(0, 1, a0, b1v); PRI0; BAR();                                    \
    _Pragma("unroll") for (int i = 0; i < 4; ++i) {                          \
      a1[i][0] = *(const f16x8*)&lds[(PC) + cab + 16384 + i * 2048 + lof0];  \
      a1[i][1] = *(const f16x8*)&lds[(PC) + cab + 16384 + i * 2048 + lof1]; } \
    BAR();                                                                   \
    PRI1; MQ(1, 1, a1, b1v); MQ(1, 0, a1, b0); PRI0;                         \
    BW; BAR();                                                               \
  } while (0)

__global__ __launch_bounds__(512, 2)
void gemm8_main_kernel(const f16* __restrict__ Aacts,   // [16384][2048]
                      const f16* __restrict__ Wm,       // [2048][2048] W_main^T
                      const f16* __restrict__ Z1,       // [16384][64]
                      const f16* __restrict__ Wb2,      // [G][2048][64] 0.1*Wb^T
                      const float* __restrict__ b1,     // [2048]
                      const float* __restrict__ b2,     // [G][2048]
                      f16* __restrict__ Out) {          // [16384][2048]
  __shared__ __align__(16) char lds[131072];
  const int tid = threadIdx.x, lane = tid & 63, wid = tid >> 6;
  // XCD-aware swizzle: 512 blocks, 8 XCDs (each XCD owns one bn column).
  const int swz = (blockIdx.x & 7) * 64 + (blockIdx.x >> 3);
  const int bm0 = (swz & 63) * 256, bn0 = (swz >> 6) * 256;
  const int g = bm0 >> 10;
  const char* GA = (const char*)Aacts;
  const char* GB = (const char*)Wm;
  const char* GZ = (const char*)Z1;
  const char* GW2 = (const char*)(Wb2 + (size_t)g * H_ * R_);
  const float* b2g = b2 + (size_t)g * H_;

  // staging source permutation (inverse of read swizzle)
  const int srow8 = lane >> 3;
  const int scolb = ((lane & 7) ^ srow8) * 16;
  // fragment read addressing
  const int fr = lane & 15, fq = lane >> 4;
  const uint32_t lof0 = fr * 128 + ((fq * 16) ^ ((fr & 7) << 4));
  const uint32_t lof1 = lof0 ^ 64;

  const uint32_t rA0 = bm0 + wid * 16 + srow8;
  const uint32_t rB0 = bn0 + wid * 16 + srow8;
  uint32_t oA0 = rA0 * 4096 + scolb;
  uint32_t oA1 = oA0 + 128 * 4096;
  uint32_t oB0 = rB0 * 4096 + scolb;
  uint32_t oB1 = oB0 + 128 * 4096;
  uint32_t dA0 = wid * 2048;
  uint32_t dA1 = 16384 + wid * 2048;
  uint32_t dB0 = 32768 + wid * 2048;
  uint32_t dB1 = 49152 + wid * 2048;
  const uint32_t cab = (wid >> 2) * 8192;
  const uint32_t cbb = 32768 + (wid & 3) * 4096;

  f32x4 acc[2][2][4][2] = {};   // [Qm][Qn][i][j]

  // prologue: tile0 full (A0,B0,A1,B1) + tile1's A0,B0 = 12 loads; retire tile0.
  STGM(GA, oA0, dA0);
  STGM(GB, oB0, dB0);
  STGM(GA, oA1, dA1);
  STGM(GB, oB1, dB1);
  STGM(GA, oA0, dA0);
  STGM(GB, oB0, dB0);
  WV4;
  BAR();

  uint32_t oA0c = rA0 * 128 + scolb;
  uint32_t oA1c = oA0c + 128 * 128;
  uint32_t oB0c = rB0 * 128 + scolb;
  uint32_t oB1c = oB0c + 128 * 128;

  // steady: tiles 0..29
  #pragma unroll 1
  for (int it = 0; it < 15; ++it) {
    TILE3(0,
          STGM(GB, oB1, dB1), STGM(GA, oA1, dA1),
          STGM(GA, oA0, dA0), STGM(GB, oB0, dB0), WV4);
    TILE3(65536,
          STGM(GB, oB1, dB1), STGM(GA, oA1, dA1),
          STGM(GA, oA0, dA0), STGM(GB, oB0, dB0), WV4);
  }
  // t=30: P1 stages B1/A1(31) main; P2 stages A0/B0(32) = concat (128B rows)
  TILE3(0,
        STGM(GB, oB1, dB1), STGM(GA, oA1, dA1),
        STGC(GZ, oA0c, dA0), STGC(GW2, oB0c, dB0), WV4);
  // t=31: P1 stages B1/A1(32) concat; drain all at end
  TILE3(65536,
        STGC(GW2, oB1c, dB1), STGC(GZ, oA1c, dA1),
        NOSTG, NOSTG, WV0);
  // t=32: concat compute only
  TILE3(0, NOSTG, NOSTG, NOSTG, NOSTG, NOW);

  // epilogue: v = acc + b1[col] + 0.1*b2[col]; ELU; f16 store
  #pragma unroll
  for (int Qn = 0; Qn < 2; ++Qn) {
    #pragma unroll
    for (int j = 0; j < 2; ++j) {
      const int col = bn0 + Qn * 128 + (wid & 3) * 32 + j * 16 + fr;
      const float bb1 = b1[col];
      const float bb2 = ADAPT * b2g[col];
      #pragma unroll
      for (int Qm = 0; Qm < 2; ++Qm) {
        #pragma unroll
        for (int i = 0; i < 4; ++i) {
          #pragma unroll
          for (int r = 0; r < 4; ++r) {
            const int row = bm0 + Qm * 128 + (wid >> 2) * 64 + i * 16 + fq * 4 + r;
            float v = acc[Qm][Qn][i][j][r] + bb1 + bb2;
            v = v > 0.f ? v : expm1f(v);
            Out[(size_t)row * H_ + col] = (f16)v;
          }
        }
      }
    }
  }
}

enum { EPI_Z1 = 0, EPI_OUT = 1, EPI_L0 = 2 };

// ============================================================================
// Small/odd-shape GEMM with 4-deep ring-buffer pipeline (counted vmcnt). BK=32.
// ============================================================================
template <int BM, int BN, int WM, int WN, int EPI>
__global__ __launch_bounds__((BM / WM) * (BN / WN) * 64)
void gemm_db_kernel(const f16* __restrict__ A, long long lda, long long Az,
                    const f16* __restrict__ Bw, long long ldb, long long Bz,
                    long long Bg, int NT,
                    const float* __restrict__ bias1, long long b1z,
                    const float* __restrict__ bias2, long long b2z,
                    const f16* __restrict__ addmat,
                    void* __restrict__ outp, long long out_z, long long ldo,
                    int rows_per_group) {
  constexpr int NW = (BM / WM) * (BN / WN);
  constexpr int FM = WM / 16, FN = WN / 16;
  constexpr int RA = BM / (NW * 16), RB = BN / (NW * 16);
  constexpr int LPT = RA + RB;   // gl_lds per thread per tile
  const int tid = threadIdx.x, lane = tid & 63, wid = tid >> 6;
  const int bm0 = blockIdx.x * BM, bn0 = blockIdx.y * BN;
  const int z = blockIdx.z;
  const int gidx = (rows_per_group > 0) ? (bm0 / rows_per_group) : 0;

  __shared__ __align__(16) f16 As[4][BM * 32];
  __shared__ __align__(16) f16 Bs[4][BN * 32];

  const int wm0 = (wid / (BN / WN)) * WM;
  const int wn0 = (wid % (BN / WN)) * WN;
  const int srow = wid * 16 + (lane >> 2);
  const int scol = (lane & 3) * 8;
  const int fr = lane & 15, fq = lane >> 4;

  const f16* pa = A + (long long)z * Az + (long long)(bm0 + srow) * lda + scol;
  const f16* pb = Bw + (long long)z * Bz + (long long)gidx * Bg +
                  (long long)(bn0 + srow) * ldb + scol;
  const long long stA = (long long)(NW * 16) * lda;
  const long long stB = (long long)(NW * 16) * ldb;

  f32x4 acc[FM][FN] = {};

  auto stage = [&](int t) {
    const f16* qa = pa + t * 32;
    const f16* qb = pb + t * 32;
    const int b = t & 3;
    #pragma unroll
    for (int r = 0; r < RA; ++r)
      gl_lds16(qa + r * stA, &As[b][(r * NW + wid) * 512]);
    #pragma unroll
    for (int r = 0; r < RB; ++r)
      gl_lds16(qb + r * stB, &Bs[b][(r * NW + wid) * 512]);
  };
  auto comp = [&](int t) {
    const int b = t & 3;
    f16x8 af[FM], bf[FN];
    #pragma unroll
    for (int i = 0; i < FM; ++i)
      af[i] = *(const f16x8*)&As[b][(wm0 + i * 16 + fr) * 32 + fq * 8];
    #pragma unroll
    for (int j = 0; j < FN; ++j)
      bf[j] = *(const f16x8*)&Bs[b][(wn0 + j * 16 + fr) * 32 + fq * 8];
    #pragma unroll
    for (int i = 0; i < FM; ++i)
      #pragma unroll
      for (int j = 0; j < FN; ++j)
        acc[i][j] = __builtin_amdgcn_mfma_f32_16x16x32_f16(af[i], bf[j], acc[i][j], 0, 0, 0);
  };

  if (NT <= 4) {
    for (int t = 0; t < NT; ++t) stage(t);
    wvc<0>();
    BAR();
    for (int t = 0; t < NT; ++t) comp(t);
  } else {
    stage(0); stage(1); stage(2); stage(3);
    int t = 0;
    #pragma unroll 1
    for (; t < NT - 4; ++t) {
      wvc<3 * LPT>();
      BAR();
      comp(t);
      BAR();
      stage(t + 4);
    }
    wvc<3 * LPT>(); BAR(); comp(t); BAR(); ++t;
    wvc<2 * LPT>(); BAR(); comp(t); BAR(); ++t;
    wvc<1 * LPT>(); BAR(); comp(t); BAR(); ++t;
    wvc<0>();       BAR(); comp(t);
  }

  const float* b1p = bias1 ? bias1 + (long long)z * b1z : nullptr;
  const float* b2p = bias2 ? bias2 + (long long)gidx * b2z : nullptr;
  #pragma unroll
  for (int i = 0; i < FM; ++i) {
    #pragma unroll
    for (int j = 0; j < FN; ++j) {
      const int col = bn0 + wn0 + j * 16 + fr;
      const float b1 = b1p ? b1p[col] : 0.f;
      const float b2v = b2p ? ADAPT * b2p[col] : 0.f;
      #pragma unroll
      for (int r = 0; r < 4; ++r) {
        const int row = bm0 + wm0 + i * 16 + fq * 4 + r;
        float v = acc[i][j][r] + b1 + b2v;
        if constexpr (EPI == EPI_L0) {
          v += (float)addmat[(long long)(row & (B_ - 1)) * H_ + col];
          v = v > 0.f ? v : expm1f(v);
          ((f16*)outp)[(long long)row * ldo + col] = (f16)v;
        } else if constexpr (EPI == EPI_Z1) {
          ((f16*)outp)[(long long)z * out_z + (long long)row * ldo + col] = (f16)v;
        } else {  // EPI_OUT: group-major row -> [B, G, A] fp32
          const int g = row >> 10, b = row & 1023;
          ((float*)outp)[((long long)b * G_ + g) * A_ + col] = v;
        }
      }
    }
  }
}

extern "C" void kernel_launch(void* const* d_in, const int* in_sizes, int n_in,
                              void* d_out, int out_size, void* d_ws, size_t ws_size,
                              hipStream_t stream) {
  const float* s      = (const float*)d_in[0];
  const float* W_in   = (const float*)d_in[1];
  const float* b_in   = (const float*)d_in[2];
  const float* W_main = (const float*)d_in[3];
  const float* b_main = (const float*)d_in[4];
  const float* Wa     = (const float*)d_in[5];
  const float* ba     = (const float*)d_in[6];
  const float* Wb     = (const float*)d_in[7];
  const float* bb     = (const float*)d_in[8];
  const float* W_out  = (const float*)d_in[9];
  const float* b_out  = (const float*)d_in[10];

  char* ws = (char*)d_ws;
  size_t off = 0;
  auto alloc = [&](size_t bytes) -> void* {
    void* p = ws + off;
    off += (bytes + 255) & ~(size_t)255;
    return p;
  };
  f16* sh   = (f16*)alloc((size_t)B_ * S_ * 2);
  f16* Wint = (f16*)alloc((size_t)H_ * S_ * 2);
  f16* Wmt  = (f16*)alloc((size_t)L_ * H_ * H_ * 2);
  f16* Wat  = (f16*)alloc((size_t)L_ * G_ * R_ * H_ * 2);
  f16* Wbt  = (f16*)alloc((size_t)L_ * G_ * H_ * R_ * 2);
  f16* Wot  = (f16*)alloc((size_t)A_ * H_ * 2);
  f16* xh0  = (f16*)alloc((size_t)G_ * B_ * H_ * 2);
  f16* xh1  = (f16*)alloc((size_t)G_ * B_ * H_ * 2);
  f16* z1h  = (f16*)alloc((size_t)G_ * B_ * R_ * 2);
  f16* x0h  = xh1;                     // aliases: dead before xh1 first written
  f16* y0h  = xh1 + (size_t)B_ * H_;

  // all conversions/transposes in ONE launch
  prep_kernel<<<36352, dim3(32, 8), 0, stream>>>(
      s, sh, W_in, Wint, W_main, Wmt, Wa, Wat, Wb, Wbt, W_out, Wot);

  // x0 = s @ W_in + b_in  [B, H]
  gemm_db_kernel<64, 128, 32, 64, EPI_Z1><<<dim3(B_ / 64, H_ / 128, 1), 256, 0, stream>>>(
      sh, S_, 0, Wint, S_, 0, 0, S_ / 32,
      b_in, 0, nullptr, 0, nullptr, x0h, 0, H_, 0);

  // y0 = x0 @ W_main[0] + b_main[0]  [B, H] (group-invariant: 1/16 the work)
  gemm_db_kernel<64, 128, 32, 64, EPI_Z1><<<dim3(B_ / 64, H_ / 128, 1), 256, 0, stream>>>(
      x0h, H_, 0, Wmt, H_, 0, 0, H_ / 32,
      b_main, 0, nullptr, 0, nullptr, y0h, 0, H_, 0);

  // layer-0 z1[g] = x0 @ Wa[0,g] + ba[0,g]  (Az=0: shared x0)
  gemm_db_kernel<64, 64, 32, 32, EPI_Z1><<<dim3(B_ / 64, 1, G_), 256, 0, stream>>>(
      x0h, H_, 0, Wat, H_, (long long)R_ * H_, 0, H_ / 32,
      ba, R_, nullptr, 0, nullptr, z1h, (long long)B_ * R_, R_, 0);

  // layer-0 combine: x1 = elu(y0 + z1 @ (0.1*Wb[0,g]) + 0.1*bb[0,g]) -> [G,B,H]
  gemm_db_kernel<128, 128, 64, 64, EPI_L0><<<dim3(G_ * B_ / 128, H_ / 128, 1), 256, 0, stream>>>(
      z1h, R_, 0, Wbt, R_, 0, (long long)H_ * R_, R_ / 32,
      nullptr, 0, bb, H_, y0h, xh0, 0, H_, B_);

  f16* cur = xh0;
  f16* nxt = xh1;
  for (int l = 1; l < L_; ++l) {
    gemm_db_kernel<64, 64, 32, 32, EPI_Z1><<<dim3(B_ / 64, 1, G_), 256, 0, stream>>>(
        cur, H_, (long long)B_ * H_,
        Wat + (size_t)l * G_ * R_ * H_, H_, (long long)R_ * H_, 0, H_ / 32,
        ba + (size_t)l * G_ * R_, R_, nullptr, 0, nullptr,
        z1h, (long long)B_ * R_, R_, 0);
    // 3-phase 256^2 main GEMM with fused adapter concat-K and ELU epilogue
    gemm8_main_kernel<<<512, 512, 0, stream>>>(
        cur, Wmt + (size_t)l * H_ * H_, z1h, Wbt + (size_t)l * G_ * H_ * R_,
        b_main + (size_t)l * H_, bb + (size_t)l * G_ * H_, nxt);
    f16* t = cur; cur = nxt; nxt = t;
  }

  // output: logits[b,g,:] = x @ W_out + b_out (fp32, permuted store)
  gemm_db_kernel<128, 128, 64, 64, EPI_OUT><<<dim3(G_ * B_ / 128, A_ / 128, 1), 256, 0, stream>>>(
      cur, H_, 0, Wot, H_, 0, 0, H_ / 32,
      b_out, 0, nullptr, 0, nullptr, d_out, 0, A_, 0);
}